// Round 6
// baseline (2241.264 us; speedup 1.0000x reference)
//
#include <hip/hip_runtime.h>
#include <cstdint>
#include <cstddef>

// Problem dims (fixed by reference)
#define B_    64
#define T_    4096
#define H_    128
#define C1_   64
#define NCLS_ 40

#define LOG2E_     1.4426950408889634f
#define TWOLOG2E_  2.8853900817779268f
#define NEG4LOG2E_ (-5.7707801635558536f)   // -2 * 2log2e

typedef _Float16 half2_t __attribute__((ext_vector_type(2)));
typedef _Float16 half8_t __attribute__((ext_vector_type(8)));
typedef float    f32x4_t __attribute__((ext_vector_type(4)));

__device__ __forceinline__ half2_t pack2(float a, float b){
  half2_t r; r.x = (_Float16)a; r.y = (_Float16)b; return r;   // RTNE
}
template<int CTRL>
__device__ __forceinline__ unsigned qdpp(unsigned x){
  return (unsigned)__builtin_amdgcn_update_dpp(0, (int)x, CTRL, 0xF, 0xF, true);
}

// ---------------- kernel 1: 3x3 second-moment stats of x over B*T ----------------
__global__ __launch_bounds__(256) void stats_kernel(const float* __restrict__ x,
                                                    float* __restrict__ stats){
  int t = blockIdx.x * 256 + threadIdx.x;
  const float4* xv = (const float4*)x + (size_t)t * 3;
  float4 a = xv[0], b = xv[1], c = xv[2];
  float x0[4] = {a.x, a.w, b.z, c.y};
  float x1[4] = {a.y, b.x, b.w, c.z};
  float x2[4] = {a.z, b.y, c.x, c.w};
  float s[9] = {0,0,0,0,0,0,0,0,0};
  #pragma unroll
  for (int r=0;r<4;++r){
    s[0]+=x0[r]; s[1]+=x1[r]; s[2]+=x2[r];
    s[3]+=x0[r]*x0[r]; s[4]+=x0[r]*x1[r]; s[5]+=x0[r]*x2[r];
    s[6]+=x1[r]*x1[r]; s[7]+=x1[r]*x2[r]; s[8]+=x2[r]*x2[r];
  }
  __shared__ float red[9][256];
  #pragma unroll
  for (int j=0;j<9;++j) red[j][threadIdx.x] = s[j];
  __syncthreads();
  if (threadIdx.x < 9){
    float sum = 0.f;
    for (int i=0;i<256;++i) sum += red[threadIdx.x][i];
    atomicAdd(&stats[threadIdx.x], sum);
  }
}

// Fold conv + BN(train stats) + gamma/beta into per-channel affine. conv_b cancels.
__device__ __forceinline__ void chan_affine(int c, const float* __restrict__ conv_w,
    const float* __restrict__ bn_g, const float* __restrict__ bn_b,
    const float* __restrict__ stats,
    float& A0, float& A1, float& A2, float& Bc){
  const float Ninv = 1.0f / (float)(B_*T_);
  float m0=stats[0]*Ninv, m1=stats[1]*Ninv, m2=stats[2]*Ninv;
  float c00=stats[3]*Ninv-m0*m0, c01=stats[4]*Ninv-m0*m1, c02=stats[5]*Ninv-m0*m2;
  float c11=stats[6]*Ninv-m1*m1, c12=stats[7]*Ninv-m1*m2, c22=stats[8]*Ninv-m2*m2;
  float w0=conv_w[c*3+0], w1=conv_w[c*3+1], w2=conv_w[c*3+2];
  float var = w0*(w0*c00 + 2.f*(w1*c01 + w2*c02)) + w1*(w1*c11 + 2.f*w2*c12) + w2*w2*c22;
  float sc = bn_g[c] * rsqrtf(var + 1e-5f);
  A0 = w0*sc; A1 = w1*sc; A2 = w2*sc;
  Bc = bn_b[c] - (w0*m0 + w1*m1 + w2*m2)*sc;
}

// ---------------- fused persistent LSTM, transposed-MFMA recurrence ----------------
// 64 blocks x 512 threads (8 waves, 2/SIMD — R5 showed 1/SIMD exposes latency: keep 2).
// Blob per 16-step chunk: P[s][n] = sg*(W_ih.relu(affine(x)) + b_ih + b_hh) -> LDS
// (row s, dword col (n&127)*4 + gate, stride 516 dw).
// Recurrence per step on the MATRIX pipe, TRANSPOSED: D = A(h-bcast) x B(W_hh^T).
//   h fetched with ONE ds_read_b128/lane: lane (rfrag,kgrp) reads slice
//   h[(lane&3)*32 + kgrp*8 .. +8); the four A-frags (A[k]=h[kc*32+kgrp*8+j]) are
//   rebuilt via 16 v_mov_dpp quad_perm broadcasts (ctrl=kc*0x55) — moves the
//   redistribution off the CU-shared LDS pipe (48 -> 24 LDS instr/CU/step).
//   B-frag: sg*w_hh[g*128 + wv*16 + rfrag][kc*32 + kgrp*8 + j], stationary in VGPR.
//   MFMA chains split 2+2 (dA: kc0,2; dB: kc1,3) + scalar add — shorter dep chain.
//   D cols = elements, rows replicated -> lane reads [0]; lane owns element
//   wv*16+rfrag, all 4 gates in-lane (kgrp 4x redundant; kgrp==0 writes h).
// cs carried scaled by 2log2e. One barrier per step, lgkmcnt-only drain. pq (lane's
// element's 4 gates) one b128, prefetched 1 step ahead; chunk-boundary WAR safe
// (all chunk P reads drain at the step-15 barrier).
__global__ __launch_bounds__(512,2) void lstm_fused_kernel(
    const float* __restrict__ x,
    const float* __restrict__ conv_w, const float* __restrict__ bn_g,
    const float* __restrict__ bn_b, const float* __restrict__ stats,
    const float* __restrict__ w_ih, const float* __restrict__ b_ih,
    const float* __restrict__ b_hh, const float* __restrict__ w_hh,
    const float* __restrict__ h0, const float* __restrict__ c0,
    const float* __restrict__ out_w, const float* __restrict__ out_b,
    float* __restrict__ out){
  constexpr int CH   = 16;    // steps per chunk
  constexpr int PSTR = 516;   // P row stride in dwords: 516*4 = 2064 B, 16B aligned
  int b = blockIdx.x, t = threadIdx.x;
  int lane = t & 63, wv = t >> 6;
  int rfrag = lane & 15, kgrp = lane >> 4;
  int estar = wv*16 + rfrag;                      // this lane's h element
  bool wrt = (kgrp == 0);

  __shared__ __align__(16) _Float16 hbuf[2][H_];
  __shared__ __align__(16) float P_lds[CH * PSTR];
  __shared__ __align__(16) float4 cf_lds[C1_];

  if (t < C1_){
    float A0,A1,A2,Bc; chan_affine(t, conv_w, bn_g, bn_b, stats, A0,A1,A2,Bc);
    cf_lds[t] = make_float4(A0,A1,A2,Bc);
  }

  // ---- stationary recurrent weights as B-frags: Wf[g][kc], sg prescale folded ----
  half8_t Wf[4][4];
  #pragma unroll
  for (int g=0; g<4; ++g){
    float sg = (g==2) ? TWOLOG2E_ : -LOG2E_;
    #pragma unroll
    for (int kc=0; kc<4; ++kc){
      const float4* wp = (const float4*)(w_hh + (size_t)(g*H_ + wv*16 + rfrag)*H_ + kc*32 + kgrp*8);
      float4 u0 = wp[0], u1 = wp[1];
      half8_t hv;
      hv[0]=(_Float16)(sg*u0.x); hv[1]=(_Float16)(sg*u0.y);
      hv[2]=(_Float16)(sg*u0.z); hv[3]=(_Float16)(sg*u0.w);
      hv[4]=(_Float16)(sg*u1.x); hv[5]=(_Float16)(sg*u1.y);
      hv[6]=(_Float16)(sg*u1.z); hv[7]=(_Float16)(sg*u1.w);
      Wf[g][kc] = hv;
    }
  }
  // ---- producer B-frags (W_ih) + folded biases: wave wv owns n = g*128+wv*16+rfrag ----
  half8_t bf[4][2];
  float sgb[4];
  #pragma unroll
  for (int g=0; g<4; ++g){
    int n = g*H_ + wv*16 + rfrag;
    float sg = (g==2) ? TWOLOG2E_ : -LOG2E_;
    sgb[g] = sg * (b_ih[n] + b_hh[n]);
    #pragma unroll
    for (int kh=0; kh<2; ++kh){
      const float4* wp = (const float4*)(w_ih + (size_t)n*C1_ + kh*32 + kgrp*8);
      float4 u0 = wp[0], u1 = wp[1];
      half8_t hv;
      hv[0]=(_Float16)(sg*u0.x); hv[1]=(_Float16)(sg*u0.y);
      hv[2]=(_Float16)(sg*u0.z); hv[3]=(_Float16)(sg*u0.w);
      hv[4]=(_Float16)(sg*u1.x); hv[5]=(_Float16)(sg*u1.y);
      hv[6]=(_Float16)(sg*u1.z); hv[7]=(_Float16)(sg*u1.w);
      bf[g][kh] = hv;
    }
  }

  float cs = TWOLOG2E_ * c0[(size_t)b*H_ + estar];   // scaled cell state (kgrp-redundant)
  if (wrt) hbuf[0][estar] = (_Float16)h0[(size_t)b*H_ + estar];

  // ---- x prefetch for chunk 0 (producer A-row = timestep rfrag) ----
  const float* xb = x + (size_t)b*T_*3;
  float xp0, xp1, xp2;
  { const float* p = xb + 3*rfrag; xp0 = p[0]; xp1 = p[1]; xp2 = p[2]; }
  const f32x4_t Z = {0.f, 0.f, 0.f, 0.f};            // hoisted MFMA C-init
  int hsl = (lane & 3)*32 + kgrp*8;                  // this lane's h-slice offset
  __syncthreads();

  for (int c = 0; c < T_/CH; ++c){
    // ===== blob: P tile for steps [c*16, c*16+16) =====
    half8_t a0, a1;
    #pragma unroll
    for (int j=0;j<8;++j){
      float4 q = cf_lds[kgrp*8+j];
      a0[j] = (_Float16)fmaxf(fmaf(q.x,xp0, fmaf(q.y,xp1, fmaf(q.z,xp2, q.w))), 0.f);
      float4 rr = cf_lds[32+kgrp*8+j];
      a1[j] = (_Float16)fmaxf(fmaf(rr.x,xp0, fmaf(rr.y,xp1, fmaf(rr.z,xp2, rr.w))), 0.f);
    }
    { int row = (c+1)*CH + rfrag; row = (row < T_) ? row : (T_-1);
      const float* p = xb + 3*row; xp0 = p[0]; xp1 = p[1]; xp2 = p[2]; }
    #pragma unroll
    for (int g=0; g<4; ++g){
      f32x4_t dp = __builtin_amdgcn_mfma_f32_16x16x32_f16(a0, bf[g][0], Z, 0, 0, 0);
      dp = __builtin_amdgcn_mfma_f32_16x16x32_f16(a1, bf[g][1], dp, 0, 0, 0);
      int col = (wv*16 + rfrag)*4 + g;             // element-major, gate-minor
      #pragma unroll
      for (int v4=0; v4<4; ++v4)
        P_lds[(kgrp*4 + v4)*PSTR + col] = dp[v4] + sgb[g];
    }
    asm volatile("s_waitcnt lgkmcnt(0)" ::: "memory");
    __builtin_amdgcn_s_barrier();                  // serves as step-0 barrier too
    asm volatile("" ::: "memory");

    // pq for step 0: lane's element, 4 gates, one b128
    f32x4_t pq = *(const f32x4_t*)(P_lds + (size_t)estar*4);

    // ===== 16 recurrence steps =====
    #pragma unroll
    for (int s=0; s<CH; ++s){
      int p = s & 1;                               // c*16 even -> parity == s&1
      if (s > 0){
        asm volatile("s_waitcnt lgkmcnt(0)" ::: "memory");
        __builtin_amdgcn_s_barrier();
        asm volatile("" ::: "memory");
      }
      // ONE b128 h fetch: lane's slice (kc=lane&3, kgrp)
      uint4 hr = *(const uint4*)(hbuf[p] + hsl);
      f32x4_t pqn = pq;
      if (s < CH-1) pqn = *(const f32x4_t*)(P_lds + (size_t)(s+1)*PSTR + estar*4);
      // rebuild A-frags via quad_perm broadcasts (VALU pipe, not LDS)
      uint4 u0, u1, u2, u3;
      u0.x = qdpp<0x00>(hr.x); u0.y = qdpp<0x00>(hr.y); u0.z = qdpp<0x00>(hr.z); u0.w = qdpp<0x00>(hr.w);
      u1.x = qdpp<0x55>(hr.x); u1.y = qdpp<0x55>(hr.y); u1.z = qdpp<0x55>(hr.z); u1.w = qdpp<0x55>(hr.w);
      u2.x = qdpp<0xAA>(hr.x); u2.y = qdpp<0xAA>(hr.y); u2.z = qdpp<0xAA>(hr.z); u2.w = qdpp<0xAA>(hr.w);
      u3.x = qdpp<0xFF>(hr.x); u3.y = qdpp<0xFF>(hr.y); u3.z = qdpp<0xFF>(hr.z); u3.w = qdpp<0xFF>(hr.w);
      half8_t A0 = __builtin_bit_cast(half8_t, u0);
      half8_t A1 = __builtin_bit_cast(half8_t, u1);
      half8_t A2 = __builtin_bit_cast(half8_t, u2);
      half8_t A3 = __builtin_bit_cast(half8_t, u3);
      // split 2+2 chains per gate (shorter dep chain than 4-deep)
      f32x4_t dA0 = __builtin_amdgcn_mfma_f32_16x16x32_f16(A0, Wf[0][0], Z, 0,0,0);
      f32x4_t dA1 = __builtin_amdgcn_mfma_f32_16x16x32_f16(A0, Wf[1][0], Z, 0,0,0);
      f32x4_t dA2 = __builtin_amdgcn_mfma_f32_16x16x32_f16(A0, Wf[2][0], Z, 0,0,0);
      f32x4_t dA3 = __builtin_amdgcn_mfma_f32_16x16x32_f16(A0, Wf[3][0], Z, 0,0,0);
      f32x4_t dB0 = __builtin_amdgcn_mfma_f32_16x16x32_f16(A1, Wf[0][1], Z, 0,0,0);
      f32x4_t dB1 = __builtin_amdgcn_mfma_f32_16x16x32_f16(A1, Wf[1][1], Z, 0,0,0);
      f32x4_t dB2 = __builtin_amdgcn_mfma_f32_16x16x32_f16(A1, Wf[2][1], Z, 0,0,0);
      f32x4_t dB3 = __builtin_amdgcn_mfma_f32_16x16x32_f16(A1, Wf[3][1], Z, 0,0,0);
      dA0 = __builtin_amdgcn_mfma_f32_16x16x32_f16(A2, Wf[0][2], dA0, 0,0,0);
      dA1 = __builtin_amdgcn_mfma_f32_16x16x32_f16(A2, Wf[1][2], dA1, 0,0,0);
      dA2 = __builtin_amdgcn_mfma_f32_16x16x32_f16(A2, Wf[2][2], dA2, 0,0,0);
      dA3 = __builtin_amdgcn_mfma_f32_16x16x32_f16(A2, Wf[3][2], dA3, 0,0,0);
      dB0 = __builtin_amdgcn_mfma_f32_16x16x32_f16(A3, Wf[0][3], dB0, 0,0,0);
      dB1 = __builtin_amdgcn_mfma_f32_16x16x32_f16(A3, Wf[1][3], dB1, 0,0,0);
      dB2 = __builtin_amdgcn_mfma_f32_16x16x32_f16(A3, Wf[2][3], dB2, 0,0,0);
      dB3 = __builtin_amdgcn_mfma_f32_16x16x32_f16(A3, Wf[3][3], dB3, 0,0,0);
      // component 0 == lane's element (rows replicated) — no picks
      float vI = (dA0[0] + dB0[0]) + pq[0];
      float vF = (dA1[0] + dB1[0]) + pq[1];
      float vG = (dA2[0] + dB2[0]) + pq[2];
      float vO = (dA3[0] + dB3[0]) + pq[3];
      float rI = __builtin_amdgcn_rcpf(1.f + __builtin_amdgcn_exp2f(vI));  // sigmoid(i)
      float rF = __builtin_amdgcn_rcpf(1.f + __builtin_amdgcn_exp2f(vF));  // sigmoid(f)
      float rG = __builtin_amdgcn_rcpf(1.f + __builtin_amdgcn_exp2f(vG));  // -> tanh(g)
      float rO = __builtin_amdgcn_rcpf(1.f + __builtin_amdgcn_exp2f(vO));  // sigmoid(o)
      float gT2 = fmaf(NEG4LOG2E_, rG, TWOLOG2E_);   // 2log2e * tanh(g)
      float cn  = fmaf(rF, cs, rI * gT2);            // scaled c'
      cs = cn;
      float th = fmaf(-2.f, __builtin_amdgcn_rcpf(1.f + __builtin_amdgcn_exp2f(cn)), 1.f);
      float h  = rO * th;
      if (wrt) hbuf[1-p][estar] = (_Float16)h;
      pq = pqn;
    }
  }
  __syncthreads();
  // classifier epilogue on final h (T even -> buffer 0)
  if (t < NCLS_){
    float s = out_b[t];
    #pragma unroll 8
    for (int kk=0; kk<H_; ++kk)
      s = fmaf(out_w[t*H_ + kk], (float)hbuf[0][kk], s);
    out[(size_t)b*NCLS_ + t] = s;
  }
}

extern "C" void kernel_launch(void* const* d_in, const int* in_sizes, int n_in,
                              void* d_out, int out_size, void* d_ws, size_t ws_size,
                              hipStream_t stream){
  const float* x      = (const float*)d_in[0];
  const float* conv_w = (const float*)d_in[1];
  // d_in[2] = conv_b: cancels exactly inside BN(train stats) — unused
  const float* bn_g   = (const float*)d_in[3];
  const float* bn_b   = (const float*)d_in[4];
  const float* w_ih   = (const float*)d_in[5];
  const float* b_ih   = (const float*)d_in[6];
  const float* w_hh   = (const float*)d_in[7];
  const float* b_hh   = (const float*)d_in[8];
  const float* out_w  = (const float*)d_in[9];
  const float* out_b  = (const float*)d_in[10];
  const float* h0     = (const float*)d_in[11];
  const float* c0     = (const float*)d_in[12];
  float* out   = (float*)d_out;
  float* stats = (float*)d_ws;

  hipMemsetAsync(d_ws, 0, 64, stream);
  stats_kernel<<<256, 256, 0, stream>>>(x, stats);
  lstm_fused_kernel<<<B_, 512, 0, stream>>>(x, conv_w, bn_g, bn_b, stats,
                                            w_ih, b_ih, b_hh, w_hh, h0, c0,
                                            out_w, out_b, out);
}

// Round 7
// 2031.996 us; speedup vs baseline: 1.1030x; 1.1030x over previous
//
#include <hip/hip_runtime.h>
#include <cstdint>
#include <cstddef>

// Problem dims (fixed by reference)
#define B_    64
#define T_    4096
#define H_    128
#define C1_   64
#define NCLS_ 40

#define LOG2E_     1.4426950408889634f
#define TWOLOG2E_  2.8853900817779268f
#define NEG4LOG2E_ (-5.7707801635558536f)   // -2 * 2log2e

typedef _Float16 half2_t __attribute__((ext_vector_type(2)));
typedef _Float16 half8_t __attribute__((ext_vector_type(8)));
typedef float    f32x4_t __attribute__((ext_vector_type(4)));

__device__ __forceinline__ half2_t pack2(float a, float b){
  half2_t r; r.x = (_Float16)a; r.y = (_Float16)b; return r;   // RTNE
}

// ---------------- kernel 1: 3x3 second-moment stats of x over B*T ----------------
__global__ __launch_bounds__(256) void stats_kernel(const float* __restrict__ x,
                                                    float* __restrict__ stats){
  int t = blockIdx.x * 256 + threadIdx.x;
  const float4* xv = (const float4*)x + (size_t)t * 3;
  float4 a = xv[0], b = xv[1], c = xv[2];
  float x0[4] = {a.x, a.w, b.z, c.y};
  float x1[4] = {a.y, b.x, b.w, c.z};
  float x2[4] = {a.z, b.y, c.x, c.w};
  float s[9] = {0,0,0,0,0,0,0,0,0};
  #pragma unroll
  for (int r=0;r<4;++r){
    s[0]+=x0[r]; s[1]+=x1[r]; s[2]+=x2[r];
    s[3]+=x0[r]*x0[r]; s[4]+=x0[r]*x1[r]; s[5]+=x0[r]*x2[r];
    s[6]+=x1[r]*x1[r]; s[7]+=x1[r]*x2[r]; s[8]+=x2[r]*x2[r];
  }
  __shared__ float red[9][256];
  #pragma unroll
  for (int j=0;j<9;++j) red[j][threadIdx.x] = s[j];
  __syncthreads();
  if (threadIdx.x < 9){
    float sum = 0.f;
    for (int i=0;i<256;++i) sum += red[threadIdx.x][i];
    atomicAdd(&stats[threadIdx.x], sum);
  }
}

// Fold conv + BN(train stats) + gamma/beta into per-channel affine. conv_b cancels.
__device__ __forceinline__ void chan_affine(int c, const float* __restrict__ conv_w,
    const float* __restrict__ bn_g, const float* __restrict__ bn_b,
    const float* __restrict__ stats,
    float& A0, float& A1, float& A2, float& Bc){
  const float Ninv = 1.0f / (float)(B_*T_);
  float m0=stats[0]*Ninv, m1=stats[1]*Ninv, m2=stats[2]*Ninv;
  float c00=stats[3]*Ninv-m0*m0, c01=stats[4]*Ninv-m0*m1, c02=stats[5]*Ninv-m0*m2;
  float c11=stats[6]*Ninv-m1*m1, c12=stats[7]*Ninv-m1*m2, c22=stats[8]*Ninv-m2*m2;
  float w0=conv_w[c*3+0], w1=conv_w[c*3+1], w2=conv_w[c*3+2];
  float var = w0*(w0*c00 + 2.f*(w1*c01 + w2*c02)) + w1*(w1*c11 + 2.f*w2*c12) + w2*w2*c22;
  float sc = bn_g[c] * rsqrtf(var + 1e-5f);
  A0 = w0*sc; A1 = w1*sc; A2 = w2*sc;
  Bc = bn_b[c] - (w0*m0 + w1*m1 + w2*m2)*sc;
}

// ---------------- fused persistent LSTM, transposed-MFMA recurrence ----------------
// 64 blocks x 512 threads (8 waves, 2/SIMD — R5: 1/SIMD exposes latency; R6: DPP
// redistribution lengthens the load->MFMA path. This is R4's structure with ONE
// change: MFMA chains fully split).
// Blob per 16-step chunk: P[s][n] = sg*(W_ih.relu(affine(x)) + b_ih + b_hh) -> LDS
// (row s, dword col (n&127)*4 + gate, stride 516 dw).
// Recurrence per step on the MATRIX pipe, TRANSPOSED: D = A(h-bcast) x B(W_hh^T).
//   A-frag: A[r][k] = h[kc*32 + kgrp*8 + j] — row-independent -> all D rows equal.
//   B-frag: B[k][n] = sg*w_hh[g*128 + wv*16 + rfrag][kc*32 + kgrp*8 + j], stationary.
//   16 INDEPENDENT MFMAs (C = hoisted Z) + 2-level add tree per gate: critical path
//   = 1 mfma latency + 2 adds instead of 4 chained mfma latencies. MFMAs consuming
//   A_kc still wait only on load kc -> staggered-load overlap preserved.
//   D[r][c] = gate-g preact of element wv*16+c, rows replicated -> lane reads [0];
//   lane owns element wv*16+rfrag, all 4 gates in-lane (kgrp 4x redundant; kgrp==0
//   writes h).
// cs carried scaled by 2log2e. One barrier per step, lgkmcnt-only drain. pq (lane's
// element's 4 gates) one b128, prefetched 1 step ahead (if(s<CH-1) is compile-time
// under full unroll); chunk-boundary WAR safe (all chunk P reads drain at the
// step-15 barrier).
__global__ __launch_bounds__(512,2) void lstm_fused_kernel(
    const float* __restrict__ x,
    const float* __restrict__ conv_w, const float* __restrict__ bn_g,
    const float* __restrict__ bn_b, const float* __restrict__ stats,
    const float* __restrict__ w_ih, const float* __restrict__ b_ih,
    const float* __restrict__ b_hh, const float* __restrict__ w_hh,
    const float* __restrict__ h0, const float* __restrict__ c0,
    const float* __restrict__ out_w, const float* __restrict__ out_b,
    float* __restrict__ out){
  constexpr int CH   = 16;    // steps per chunk
  constexpr int PSTR = 516;   // P row stride in dwords: 516*4 = 2064 B, 16B aligned
  int b = blockIdx.x, t = threadIdx.x;
  int lane = t & 63, wv = t >> 6;
  int rfrag = lane & 15, kgrp = lane >> 4;
  int estar = wv*16 + rfrag;                      // this lane's h element
  bool wrt = (kgrp == 0);

  __shared__ __align__(16) _Float16 hbuf[2][H_];
  __shared__ __align__(16) float P_lds[CH * PSTR];
  __shared__ __align__(16) float4 cf_lds[C1_];

  if (t < C1_){
    float A0,A1,A2,Bc; chan_affine(t, conv_w, bn_g, bn_b, stats, A0,A1,A2,Bc);
    cf_lds[t] = make_float4(A0,A1,A2,Bc);
  }

  // ---- stationary recurrent weights as B-frags: Wf[g][kc], sg prescale folded ----
  half8_t Wf[4][4];
  #pragma unroll
  for (int g=0; g<4; ++g){
    float sg = (g==2) ? TWOLOG2E_ : -LOG2E_;
    #pragma unroll
    for (int kc=0; kc<4; ++kc){
      const float4* wp = (const float4*)(w_hh + (size_t)(g*H_ + wv*16 + rfrag)*H_ + kc*32 + kgrp*8);
      float4 u0 = wp[0], u1 = wp[1];
      half8_t hv;
      hv[0]=(_Float16)(sg*u0.x); hv[1]=(_Float16)(sg*u0.y);
      hv[2]=(_Float16)(sg*u0.z); hv[3]=(_Float16)(sg*u0.w);
      hv[4]=(_Float16)(sg*u1.x); hv[5]=(_Float16)(sg*u1.y);
      hv[6]=(_Float16)(sg*u1.z); hv[7]=(_Float16)(sg*u1.w);
      Wf[g][kc] = hv;
    }
  }
  // ---- producer B-frags (W_ih) + folded biases: wave wv owns n = g*128+wv*16+rfrag ----
  half8_t bf[4][2];
  float sgb[4];
  #pragma unroll
  for (int g=0; g<4; ++g){
    int n = g*H_ + wv*16 + rfrag;
    float sg = (g==2) ? TWOLOG2E_ : -LOG2E_;
    sgb[g] = sg * (b_ih[n] + b_hh[n]);
    #pragma unroll
    for (int kh=0; kh<2; ++kh){
      const float4* wp = (const float4*)(w_ih + (size_t)n*C1_ + kh*32 + kgrp*8);
      float4 u0 = wp[0], u1 = wp[1];
      half8_t hv;
      hv[0]=(_Float16)(sg*u0.x); hv[1]=(_Float16)(sg*u0.y);
      hv[2]=(_Float16)(sg*u0.z); hv[3]=(_Float16)(sg*u0.w);
      hv[4]=(_Float16)(sg*u1.x); hv[5]=(_Float16)(sg*u1.y);
      hv[6]=(_Float16)(sg*u1.z); hv[7]=(_Float16)(sg*u1.w);
      bf[g][kh] = hv;
    }
  }

  float cs = TWOLOG2E_ * c0[(size_t)b*H_ + estar];   // scaled cell state (kgrp-redundant)
  if (wrt) hbuf[0][estar] = (_Float16)h0[(size_t)b*H_ + estar];

  // ---- x prefetch for chunk 0 (producer A-row = timestep rfrag) ----
  const float* xb = x + (size_t)b*T_*3;
  float xp0, xp1, xp2;
  { const float* p = xb + 3*rfrag; xp0 = p[0]; xp1 = p[1]; xp2 = p[2]; }
  const f32x4_t Z = {0.f, 0.f, 0.f, 0.f};            // hoisted MFMA C-init
  __syncthreads();

  for (int c = 0; c < T_/CH; ++c){
    // ===== blob: P tile for steps [c*16, c*16+16) =====
    half8_t a0, a1;
    #pragma unroll
    for (int j=0;j<8;++j){
      float4 q = cf_lds[kgrp*8+j];
      a0[j] = (_Float16)fmaxf(fmaf(q.x,xp0, fmaf(q.y,xp1, fmaf(q.z,xp2, q.w))), 0.f);
      float4 rr = cf_lds[32+kgrp*8+j];
      a1[j] = (_Float16)fmaxf(fmaf(rr.x,xp0, fmaf(rr.y,xp1, fmaf(rr.z,xp2, rr.w))), 0.f);
    }
    { int row = (c+1)*CH + rfrag; row = (row < T_) ? row : (T_-1);
      const float* p = xb + 3*row; xp0 = p[0]; xp1 = p[1]; xp2 = p[2]; }
    #pragma unroll
    for (int g=0; g<4; ++g){
      f32x4_t dp = __builtin_amdgcn_mfma_f32_16x16x32_f16(a0, bf[g][0], Z, 0, 0, 0);
      dp = __builtin_amdgcn_mfma_f32_16x16x32_f16(a1, bf[g][1], dp, 0, 0, 0);
      int col = (wv*16 + rfrag)*4 + g;             // element-major, gate-minor
      #pragma unroll
      for (int v4=0; v4<4; ++v4)
        P_lds[(kgrp*4 + v4)*PSTR + col] = dp[v4] + sgb[g];
    }
    asm volatile("s_waitcnt lgkmcnt(0)" ::: "memory");
    __builtin_amdgcn_s_barrier();                  // serves as step-0 barrier too
    asm volatile("" ::: "memory");

    // pq for step 0: lane's element, 4 gates, one b128
    f32x4_t pq = *(const f32x4_t*)(P_lds + (size_t)estar*4);

    // ===== 16 recurrence steps =====
    #pragma unroll
    for (int s=0; s<CH; ++s){
      int p = s & 1;                               // c*16 even -> parity == s&1
      if (s > 0){
        asm volatile("s_waitcnt lgkmcnt(0)" ::: "memory");
        __builtin_amdgcn_s_barrier();
        asm volatile("" ::: "memory");
      }
      const _Float16* hb = hbuf[p];
      // A-frags: h broadcast (16-lane same-address reads, conflict-free)
      uint4 hu0 = *(const uint4*)(hb + 0*32 + kgrp*8);
      uint4 hu1 = *(const uint4*)(hb + 1*32 + kgrp*8);
      uint4 hu2 = *(const uint4*)(hb + 2*32 + kgrp*8);
      uint4 hu3 = *(const uint4*)(hb + 3*32 + kgrp*8);
      f32x4_t pqn = pq;
      if (s < CH-1) pqn = *(const f32x4_t*)(P_lds + (size_t)(s+1)*PSTR + estar*4);
      half8_t A0 = __builtin_bit_cast(half8_t, hu0);
      half8_t A1 = __builtin_bit_cast(half8_t, hu1);
      half8_t A2 = __builtin_bit_cast(half8_t, hu2);
      half8_t A3 = __builtin_bit_cast(half8_t, hu3);
      // 16 INDEPENDENT MFMAs (C=Z): MFMA using A_kc waits only on load kc; no
      // accumulate chains. Dep depth = 1 mfma + 2-level tree.
      f32x4_t dI0 = __builtin_amdgcn_mfma_f32_16x16x32_f16(A0, Wf[0][0], Z, 0,0,0);
      f32x4_t dF0 = __builtin_amdgcn_mfma_f32_16x16x32_f16(A0, Wf[1][0], Z, 0,0,0);
      f32x4_t dG0 = __builtin_amdgcn_mfma_f32_16x16x32_f16(A0, Wf[2][0], Z, 0,0,0);
      f32x4_t dO0 = __builtin_amdgcn_mfma_f32_16x16x32_f16(A0, Wf[3][0], Z, 0,0,0);
      f32x4_t dI1 = __builtin_amdgcn_mfma_f32_16x16x32_f16(A1, Wf[0][1], Z, 0,0,0);
      f32x4_t dF1 = __builtin_amdgcn_mfma_f32_16x16x32_f16(A1, Wf[1][1], Z, 0,0,0);
      f32x4_t dG1 = __builtin_amdgcn_mfma_f32_16x16x32_f16(A1, Wf[2][1], Z, 0,0,0);
      f32x4_t dO1 = __builtin_amdgcn_mfma_f32_16x16x32_f16(A1, Wf[3][1], Z, 0,0,0);
      f32x4_t dI2 = __builtin_amdgcn_mfma_f32_16x16x32_f16(A2, Wf[0][2], Z, 0,0,0);
      f32x4_t dF2 = __builtin_amdgcn_mfma_f32_16x16x32_f16(A2, Wf[1][2], Z, 0,0,0);
      f32x4_t dG2 = __builtin_amdgcn_mfma_f32_16x16x32_f16(A2, Wf[2][2], Z, 0,0,0);
      f32x4_t dO2 = __builtin_amdgcn_mfma_f32_16x16x32_f16(A2, Wf[3][2], Z, 0,0,0);
      f32x4_t dI3 = __builtin_amdgcn_mfma_f32_16x16x32_f16(A3, Wf[0][3], Z, 0,0,0);
      f32x4_t dF3 = __builtin_amdgcn_mfma_f32_16x16x32_f16(A3, Wf[1][3], Z, 0,0,0);
      f32x4_t dG3 = __builtin_amdgcn_mfma_f32_16x16x32_f16(A3, Wf[2][3], Z, 0,0,0);
      f32x4_t dO3 = __builtin_amdgcn_mfma_f32_16x16x32_f16(A3, Wf[3][3], Z, 0,0,0);
      // component 0 == lane's element (rows replicated); 2-level tree + pq
      float vI = ((dI0[0]+dI1[0]) + (dI2[0]+dI3[0])) + pq[0];
      float vF = ((dF0[0]+dF1[0]) + (dF2[0]+dF3[0])) + pq[1];
      float vG = ((dG0[0]+dG1[0]) + (dG2[0]+dG3[0])) + pq[2];
      float vO = ((dO0[0]+dO1[0]) + (dO2[0]+dO3[0])) + pq[3];
      float rI = __builtin_amdgcn_rcpf(1.f + __builtin_amdgcn_exp2f(vI));  // sigmoid(i)
      float rF = __builtin_amdgcn_rcpf(1.f + __builtin_amdgcn_exp2f(vF));  // sigmoid(f)
      float rG = __builtin_amdgcn_rcpf(1.f + __builtin_amdgcn_exp2f(vG));  // -> tanh(g)
      float rO = __builtin_amdgcn_rcpf(1.f + __builtin_amdgcn_exp2f(vO));  // sigmoid(o)
      float gT2 = fmaf(NEG4LOG2E_, rG, TWOLOG2E_);   // 2log2e * tanh(g)
      float cn  = fmaf(rF, cs, rI * gT2);            // scaled c'
      cs = cn;
      float th = fmaf(-2.f, __builtin_amdgcn_rcpf(1.f + __builtin_amdgcn_exp2f(cn)), 1.f);
      float h  = rO * th;
      if (wrt) hbuf[1-p][estar] = (_Float16)h;
      pq = pqn;
    }
  }
  __syncthreads();
  // classifier epilogue on final h (T even -> buffer 0)
  if (t < NCLS_){
    float s = out_b[t];
    #pragma unroll 8
    for (int kk=0; kk<H_; ++kk)
      s = fmaf(out_w[t*H_ + kk], (float)hbuf[0][kk], s);
    out[(size_t)b*NCLS_ + t] = s;
  }
}

extern "C" void kernel_launch(void* const* d_in, const int* in_sizes, int n_in,
                              void* d_out, int out_size, void* d_ws, size_t ws_size,
                              hipStream_t stream){
  const float* x      = (const float*)d_in[0];
  const float* conv_w = (const float*)d_in[1];
  // d_in[2] = conv_b: cancels exactly inside BN(train stats) — unused
  const float* bn_g   = (const float*)d_in[3];
  const float* bn_b   = (const float*)d_in[4];
  const float* w_ih   = (const float*)d_in[5];
  const float* b_ih   = (const float*)d_in[6];
  const float* w_hh   = (const float*)d_in[7];
  const float* b_hh   = (const float*)d_in[8];
  const float* out_w  = (const float*)d_in[9];
  const float* out_b  = (const float*)d_in[10];
  const float* h0     = (const float*)d_in[11];
  const float* c0     = (const float*)d_in[12];
  float* out   = (float*)d_out;
  float* stats = (float*)d_ws;

  hipMemsetAsync(d_ws, 0, 64, stream);
  stats_kernel<<<256, 256, 0, stream>>>(x, stats);
  lstm_fused_kernel<<<B_, 512, 0, stream>>>(x, conv_w, bn_g, bn_b, stats,
                                            w_ih, b_ih, b_hh, w_hh, h0, c0,
                                            out_w, out_b, out);
}

// Round 9
// 1679.883 us; speedup vs baseline: 1.3342x; 1.2096x over previous
//
#include <hip/hip_runtime.h>
#include <cstdint>
#include <cstddef>

// Problem dims (fixed by reference)
#define B_    64
#define T_    4096
#define H_    128
#define C1_   64
#define NCLS_ 40

#define LOG2E_     1.4426950408889634f
#define TWOLOG2E_  2.8853900817779268f
#define NEG4LOG2E_ (-5.7707801635558536f)   // -2 * 2log2e

typedef _Float16 half2_t __attribute__((ext_vector_type(2)));
typedef _Float16 half8_t __attribute__((ext_vector_type(8)));
typedef float    f32x4_t __attribute__((ext_vector_type(4)));

__device__ __forceinline__ half2_t pack2(float a, float b){
  half2_t r; r.x = (_Float16)a; r.y = (_Float16)b; return r;   // RTNE
}

// ---------------- kernel 1: 3x3 second-moment stats of x over B*T ----------------
__global__ __launch_bounds__(256) void stats_kernel(const float* __restrict__ x,
                                                    float* __restrict__ stats){
  int t = blockIdx.x * 256 + threadIdx.x;
  const float4* xv = (const float4*)x + (size_t)t * 3;
  float4 a = xv[0], b = xv[1], c = xv[2];
  float x0[4] = {a.x, a.w, b.z, c.y};
  float x1[4] = {a.y, b.x, b.w, c.z};
  float x2[4] = {a.z, b.y, c.x, c.w};
  float s[9] = {0,0,0,0,0,0,0,0,0};
  #pragma unroll
  for (int r=0;r<4;++r){
    s[0]+=x0[r]; s[1]+=x1[r]; s[2]+=x2[r];
    s[3]+=x0[r]*x0[r]; s[4]+=x0[r]*x1[r]; s[5]+=x0[r]*x2[r];
    s[6]+=x1[r]*x1[r]; s[7]+=x1[r]*x2[r]; s[8]+=x2[r]*x2[r];
  }
  __shared__ float red[9][256];
  #pragma unroll
  for (int j=0;j<9;++j) red[j][threadIdx.x] = s[j];
  __syncthreads();
  if (threadIdx.x < 9){
    float sum = 0.f;
    for (int i=0;i<256;++i) sum += red[threadIdx.x][i];
    atomicAdd(&stats[threadIdx.x], sum);
  }
}

// Fold conv + BN(train stats) + gamma/beta into per-channel affine. conv_b cancels.
__device__ __forceinline__ void chan_affine(int c, const float* __restrict__ conv_w,
    const float* __restrict__ bn_g, const float* __restrict__ bn_b,
    const float* __restrict__ stats,
    float& A0, float& A1, float& A2, float& Bc){
  const float Ninv = 1.0f / (float)(B_*T_);
  float m0=stats[0]*Ninv, m1=stats[1]*Ninv, m2=stats[2]*Ninv;
  float c00=stats[3]*Ninv-m0*m0, c01=stats[4]*Ninv-m0*m1, c02=stats[5]*Ninv-m0*m2;
  float c11=stats[6]*Ninv-m1*m1, c12=stats[7]*Ninv-m1*m2, c22=stats[8]*Ninv-m2*m2;
  float w0=conv_w[c*3+0], w1=conv_w[c*3+1], w2=conv_w[c*3+2];
  float var = w0*(w0*c00 + 2.f*(w1*c01 + w2*c02)) + w1*(w1*c11 + 2.f*w2*c12) + w2*w2*c22;
  float sc = bn_g[c] * rsqrtf(var + 1e-5f);
  A0 = w0*sc; A1 = w1*sc; A2 = w2*sc;
  Bc = bn_b[c] - (w0*m0 + w1*m1 + w2*m2)*sc;
}

// ---------------- fused persistent LSTM, transposed-MFMA recurrence ----------------
// R4 structure verbatim — best measured (1645 us dispatch). 64 blocks x 512 threads
// (8 waves, 2/SIMD). Experiment matrix closed: R5 1/SIMD (+160us), R6 DPP
// redistribution (+554us), R7 split chains (+352us), R8 persistent setprio (crash).
// The chained, 4-read, one-barrier-per-step form is the floor of this structure;
// remaining cost is the inherent serial recurrence path, not a pipe bottleneck
// (MfmaUtil 13.8 / VALUBusy 12 / HBM 0.03% chip-wide).
//
// Blob per 16-step chunk: P[s][n] = sg*(W_ih.relu(affine(x)) + b_ih + b_hh) -> LDS
// (row s, dword col (n&127)*4 + gate, stride 516 dw).
// Recurrence per step on the MATRIX pipe, TRANSPOSED: D = A(h-bcast) x B(W_hh^T).
//   A-frag: A[r][k] = h[kc*32 + kgrp*8 + j] — row-independent -> all D rows equal.
//   B-frag: B[k][n] = sg*w_hh[g*128 + wv*16 + rfrag][kc*32 + kgrp*8 + j], stationary.
//   4 independent 4-deep MFMA chains (one per gate); D[r][c] rows replicated ->
//   lane reads [0]; lane owns element wv*16+rfrag, all 4 gates in-lane (kgrp 4x
//   redundant; kgrp==0 writes h).
// cs carried scaled by 2log2e. One barrier per step, lgkmcnt-only drain. pq (lane's
// element's 4 gates) one b128, prefetched 1 step ahead; chunk-boundary WAR safe
// (all chunk P reads drain at the step-15 barrier).
__global__ __launch_bounds__(512,2) void lstm_fused_kernel(
    const float* __restrict__ x,
    const float* __restrict__ conv_w, const float* __restrict__ bn_g,
    const float* __restrict__ bn_b, const float* __restrict__ stats,
    const float* __restrict__ w_ih, const float* __restrict__ b_ih,
    const float* __restrict__ b_hh, const float* __restrict__ w_hh,
    const float* __restrict__ h0, const float* __restrict__ c0,
    const float* __restrict__ out_w, const float* __restrict__ out_b,
    float* __restrict__ out){
  constexpr int CH   = 16;    // steps per chunk
  constexpr int PSTR = 516;   // P row stride in dwords: 516*4 = 2064 B, 16B aligned
  int b = blockIdx.x, t = threadIdx.x;
  int lane = t & 63, wv = t >> 6;
  int rfrag = lane & 15, kgrp = lane >> 4;
  int estar = wv*16 + rfrag;                      // this lane's h element
  bool wrt = (kgrp == 0);

  __shared__ __align__(16) _Float16 hbuf[2][H_];
  __shared__ __align__(16) float P_lds[CH * PSTR];
  __shared__ __align__(16) float4 cf_lds[C1_];

  if (t < C1_){
    float A0,A1,A2,Bc; chan_affine(t, conv_w, bn_g, bn_b, stats, A0,A1,A2,Bc);
    cf_lds[t] = make_float4(A0,A1,A2,Bc);
  }

  // ---- stationary recurrent weights as B-frags: Wf[g][kc], sg prescale folded ----
  half8_t Wf[4][4];
  #pragma unroll
  for (int g=0; g<4; ++g){
    float sg = (g==2) ? TWOLOG2E_ : -LOG2E_;
    #pragma unroll
    for (int kc=0; kc<4; ++kc){
      const float4* wp = (const float4*)(w_hh + (size_t)(g*H_ + wv*16 + rfrag)*H_ + kc*32 + kgrp*8);
      float4 u0 = wp[0], u1 = wp[1];
      half8_t hv;
      hv[0]=(_Float16)(sg*u0.x); hv[1]=(_Float16)(sg*u0.y);
      hv[2]=(_Float16)(sg*u0.z); hv[3]=(_Float16)(sg*u0.w);
      hv[4]=(_Float16)(sg*u1.x); hv[5]=(_Float16)(sg*u1.y);
      hv[6]=(_Float16)(sg*u1.z); hv[7]=(_Float16)(sg*u1.w);
      Wf[g][kc] = hv;
    }
  }
  // ---- producer B-frags (W_ih) + folded biases: wave wv owns n = g*128+wv*16+rfrag ----
  half8_t bf[4][2];
  float sgb[4];
  #pragma unroll
  for (int g=0; g<4; ++g){
    int n = g*H_ + wv*16 + rfrag;
    float sg = (g==2) ? TWOLOG2E_ : -LOG2E_;
    sgb[g] = sg * (b_ih[n] + b_hh[n]);
    #pragma unroll
    for (int kh=0; kh<2; ++kh){
      const float4* wp = (const float4*)(w_ih + (size_t)n*C1_ + kh*32 + kgrp*8);
      float4 u0 = wp[0], u1 = wp[1];
      half8_t hv;
      hv[0]=(_Float16)(sg*u0.x); hv[1]=(_Float16)(sg*u0.y);
      hv[2]=(_Float16)(sg*u0.z); hv[3]=(_Float16)(sg*u0.w);
      hv[4]=(_Float16)(sg*u1.x); hv[5]=(_Float16)(sg*u1.y);
      hv[6]=(_Float16)(sg*u1.z); hv[7]=(_Float16)(sg*u1.w);
      bf[g][kh] = hv;
    }
  }

  float cs = TWOLOG2E_ * c0[(size_t)b*H_ + estar];   // scaled cell state (kgrp-redundant)
  if (wrt) hbuf[0][estar] = (_Float16)h0[(size_t)b*H_ + estar];

  // ---- x prefetch for chunk 0 (producer A-row = timestep rfrag) ----
  const float* xb = x + (size_t)b*T_*3;
  float xp0, xp1, xp2;
  { const float* p = xb + 3*rfrag; xp0 = p[0]; xp1 = p[1]; xp2 = p[2]; }
  const f32x4_t Z = {0.f, 0.f, 0.f, 0.f};            // hoisted MFMA C-init
  __syncthreads();

  for (int c = 0; c < T_/CH; ++c){
    // ===== blob: P tile for steps [c*16, c*16+16) =====
    half8_t a0, a1;
    #pragma unroll
    for (int j=0;j<8;++j){
      float4 q = cf_lds[kgrp*8+j];
      a0[j] = (_Float16)fmaxf(fmaf(q.x,xp0, fmaf(q.y,xp1, fmaf(q.z,xp2, q.w))), 0.f);
      float4 rr = cf_lds[32+kgrp*8+j];
      a1[j] = (_Float16)fmaxf(fmaf(rr.x,xp0, fmaf(rr.y,xp1, fmaf(rr.z,xp2, rr.w))), 0.f);
    }
    { int row = (c+1)*CH + rfrag; row = (row < T_) ? row : (T_-1);
      const float* p = xb + 3*row; xp0 = p[0]; xp1 = p[1]; xp2 = p[2]; }
    #pragma unroll
    for (int g=0; g<4; ++g){
      f32x4_t dp = __builtin_amdgcn_mfma_f32_16x16x32_f16(a0, bf[g][0], Z, 0, 0, 0);
      dp = __builtin_amdgcn_mfma_f32_16x16x32_f16(a1, bf[g][1], dp, 0, 0, 0);
      int col = (wv*16 + rfrag)*4 + g;             // element-major, gate-minor
      #pragma unroll
      for (int v4=0; v4<4; ++v4)
        P_lds[(kgrp*4 + v4)*PSTR + col] = dp[v4] + sgb[g];
    }
    asm volatile("s_waitcnt lgkmcnt(0)" ::: "memory");
    __builtin_amdgcn_s_barrier();                  // serves as step-0 barrier too
    asm volatile("" ::: "memory");

    // pq for step 0: lane's element, 4 gates, one b128
    f32x4_t pq = *(const f32x4_t*)(P_lds + (size_t)estar*4);

    // ===== 16 recurrence steps =====
    #pragma unroll
    for (int s=0; s<CH; ++s){
      int p = s & 1;                               // c*16 even -> parity == s&1
      if (s > 0){
        asm volatile("s_waitcnt lgkmcnt(0)" ::: "memory");
        __builtin_amdgcn_s_barrier();
        asm volatile("" ::: "memory");
      }
      const _Float16* hb = hbuf[p];
      // A-frags: h broadcast (16-lane same-address reads, conflict-free)
      uint4 hu0 = *(const uint4*)(hb + 0*32 + kgrp*8);
      uint4 hu1 = *(const uint4*)(hb + 1*32 + kgrp*8);
      uint4 hu2 = *(const uint4*)(hb + 2*32 + kgrp*8);
      uint4 hu3 = *(const uint4*)(hb + 3*32 + kgrp*8);
      f32x4_t pqn = pq;
      if (s < CH-1) pqn = *(const f32x4_t*)(P_lds + (size_t)(s+1)*PSTR + estar*4);
      half8_t A0 = __builtin_bit_cast(half8_t, hu0);
      half8_t A1 = __builtin_bit_cast(half8_t, hu1);
      half8_t A2 = __builtin_bit_cast(half8_t, hu2);
      half8_t A3 = __builtin_bit_cast(half8_t, hu3);
      // 4 independent 4-deep chains on the matrix pipe; C-init from hoisted Z
      f32x4_t d0 = __builtin_amdgcn_mfma_f32_16x16x32_f16(A0, Wf[0][0], Z, 0,0,0);
      f32x4_t d1 = __builtin_amdgcn_mfma_f32_16x16x32_f16(A0, Wf[1][0], Z, 0,0,0);
      f32x4_t d2 = __builtin_amdgcn_mfma_f32_16x16x32_f16(A0, Wf[2][0], Z, 0,0,0);
      f32x4_t d3 = __builtin_amdgcn_mfma_f32_16x16x32_f16(A0, Wf[3][0], Z, 0,0,0);
      d0 = __builtin_amdgcn_mfma_f32_16x16x32_f16(A1, Wf[0][1], d0, 0,0,0);
      d1 = __builtin_amdgcn_mfma_f32_16x16x32_f16(A1, Wf[1][1], d1, 0,0,0);
      d2 = __builtin_amdgcn_mfma_f32_16x16x32_f16(A1, Wf[2][1], d2, 0,0,0);
      d3 = __builtin_amdgcn_mfma_f32_16x16x32_f16(A1, Wf[3][1], d3, 0,0,0);
      d0 = __builtin_amdgcn_mfma_f32_16x16x32_f16(A2, Wf[0][2], d0, 0,0,0);
      d1 = __builtin_amdgcn_mfma_f32_16x16x32_f16(A2, Wf[1][2], d1, 0,0,0);
      d2 = __builtin_amdgcn_mfma_f32_16x16x32_f16(A2, Wf[2][2], d2, 0,0,0);
      d3 = __builtin_amdgcn_mfma_f32_16x16x32_f16(A2, Wf[3][2], d3, 0,0,0);
      d0 = __builtin_amdgcn_mfma_f32_16x16x32_f16(A3, Wf[0][3], d0, 0,0,0);
      d1 = __builtin_amdgcn_mfma_f32_16x16x32_f16(A3, Wf[1][3], d1, 0,0,0);
      d2 = __builtin_amdgcn_mfma_f32_16x16x32_f16(A3, Wf[2][3], d2, 0,0,0);
      d3 = __builtin_amdgcn_mfma_f32_16x16x32_f16(A3, Wf[3][3], d3, 0,0,0);
      // component 0 == lane's element (rows replicated) — no picks
      float vI = d0[0] + pq[0];
      float vF = d1[0] + pq[1];
      float vG = d2[0] + pq[2];
      float vO = d3[0] + pq[3];
      float rI = __builtin_amdgcn_rcpf(1.f + __builtin_amdgcn_exp2f(vI));  // sigmoid(i)
      float rF = __builtin_amdgcn_rcpf(1.f + __builtin_amdgcn_exp2f(vF));  // sigmoid(f)
      float rG = __builtin_amdgcn_rcpf(1.f + __builtin_amdgcn_exp2f(vG));  // -> tanh(g)
      float rO = __builtin_amdgcn_rcpf(1.f + __builtin_amdgcn_exp2f(vO));  // sigmoid(o)
      float gT2 = fmaf(NEG4LOG2E_, rG, TWOLOG2E_);   // 2log2e * tanh(g)
      float cn  = fmaf(rF, cs, rI * gT2);            // scaled c'
      cs = cn;
      float th = fmaf(-2.f, __builtin_amdgcn_rcpf(1.f + __builtin_amdgcn_exp2f(cn)), 1.f);
      float h  = rO * th;
      if (wrt) hbuf[1-p][estar] = (_Float16)h;
      pq = pqn;
    }
  }
  __syncthreads();
  // classifier epilogue on final h (T even -> buffer 0)
  if (t < NCLS_){
    float s = out_b[t];
    #pragma unroll 8
    for (int kk=0; kk<H_; ++kk)
      s = fmaf(out_w[t*H_ + kk], (float)hbuf[0][kk], s);
    out[(size_t)b*NCLS_ + t] = s;
  }
}

extern "C" void kernel_launch(void* const* d_in, const int* in_sizes, int n_in,
                              void* d_out, int out_size, void* d_ws, size_t ws_size,
                              hipStream_t stream){
  const float* x      = (const float*)d_in[0];
  const float* conv_w = (const float*)d_in[1];
  // d_in[2] = conv_b: cancels exactly inside BN(train stats) — unused
  const float* bn_g   = (const float*)d_in[3];
  const float* bn_b   = (const float*)d_in[4];
  const float* w_ih   = (const float*)d_in[5];
  const float* b_ih   = (const float*)d_in[6];
  const float* w_hh   = (const float*)d_in[7];
  const float* b_hh   = (const float*)d_in[8];
  const float* out_w  = (const float*)d_in[9];
  const float* out_b  = (const float*)d_in[10];
  const float* h0     = (const float*)d_in[11];
  const float* c0     = (const float*)d_in[12];
  float* out   = (float*)d_out;
  float* stats = (float*)d_ws;

  hipMemsetAsync(d_ws, 0, 64, stream);
  stats_kernel<<<256, 256, 0, stream>>>(x, stats);
  lstm_fused_kernel<<<B_, 512, 0, stream>>>(x, conv_w, bn_g, bn_b, stats,
                                            w_ih, b_ih, b_hh, w_hh, h0, c0,
                                            out_w, out_b, out);
}